// Round 1
// baseline (92.562 us; speedup 1.0000x reference)
//
#include <hip/hip_runtime.h>

#define NGRID 64
#define NEL (NGRID*NGRID*NGRID)
#define NDOF (3*NEL)

// One thread per element:
//  - derive (i,j,k) from linear element id (e = (i*64 + j)*64 + k)
//  - type code from binarized rho at 8 corners (bit = di*4 + dj*2 + dk)
//  - gather 24 U values, 24x24 matvec with filters[type], scatter-add via atomics
__global__ __launch_bounds__(256) void fe_apply_kernel(
    const float* __restrict__ U,
    const float* __restrict__ rho,
    const float* __restrict__ filters,
    float* __restrict__ out)
{
    int e = blockIdx.x * blockDim.x + threadIdx.x;
    if (e >= NEL) return;

    int k = e & 63;
    int j = (e >> 6) & 63;
    int i = (e >> 12) & 63;
    int i1 = (i + 1) & 63;
    int j1 = (j + 1) & 63;
    int k1 = (k + 1) & 63;

    // corner node linear indices, OFFSETS order:
    // (0,0,0),(1,0,0),(0,1,0),(1,1,0),(0,0,1),(1,0,1),(0,1,1),(1,1,1)
    int nodes[8];
    nodes[0] = (i  * 64 + j ) * 64 + k;
    nodes[1] = (i1 * 64 + j ) * 64 + k;
    nodes[2] = (i  * 64 + j1) * 64 + k;
    nodes[3] = (i1 * 64 + j1) * 64 + k;
    nodes[4] = (i  * 64 + j ) * 64 + k1;
    nodes[5] = (i1 * 64 + j ) * 64 + k1;
    nodes[6] = (i  * 64 + j1) * 64 + k1;
    nodes[7] = (i1 * 64 + j1) * 64 + k1;

    // typeFilter[di][dj][dk] = 2^(di*4 + dj*2 + dk); OFFSETS order -> bits:
    const int bits[8] = {0, 4, 2, 6, 1, 5, 3, 7};
    int t = 0;
    #pragma unroll
    for (int c = 0; c < 8; ++c) {
        t |= (rho[nodes[c]] > 0.5f ? 1 : 0) << bits[c];
    }

    // gather element displacement vector
    float Ue[24];
    #pragma unroll
    for (int c = 0; c < 8; ++c) {
        int base = nodes[c] * 3;
        Ue[3 * c + 0] = U[base + 0];
        Ue[3 * c + 1] = U[base + 1];
        Ue[3 * c + 2] = U[base + 2];
    }

    // 24x24 matvec; rows are 96 B (16B-aligned) -> float4 loads
    const float4* __restrict__ Krow = (const float4*)(filters + t * 576);
    #pragma unroll
    for (int r = 0; r < 24; ++r) {
        float acc = 0.0f;
        #pragma unroll
        for (int q = 0; q < 6; ++q) {
            float4 f = Krow[r * 6 + q];
            acc = fmaf(f.x, Ue[4 * q + 0], acc);
            acc = fmaf(f.y, Ue[4 * q + 1], acc);
            acc = fmaf(f.z, Ue[4 * q + 2], acc);
            acc = fmaf(f.w, Ue[4 * q + 3], acc);
        }
        atomicAdd(&out[nodes[r / 3] * 3 + (r % 3)], acc);
    }
}

extern "C" void kernel_launch(void* const* d_in, const int* in_sizes, int n_in,
                              void* d_out, int out_size, void* d_ws, size_t ws_size,
                              hipStream_t stream) {
    const float* U       = (const float*)d_in[0];
    const float* rho     = (const float*)d_in[1];
    // d_in[2] = nodIdx (recomputed arithmetically), d_in[4] = typeFilter (baked in)
    const float* filters = (const float*)d_in[3];
    float* out = (float*)d_out;

    // atomics accumulate -> must zero output every call (harness poisons 0xAA)
    hipMemsetAsync(out, 0, (size_t)out_size * sizeof(float), stream);

    dim3 block(256);
    dim3 grid(NEL / 256);
    fe_apply_kernel<<<grid, block, 0, stream>>>(U, rho, filters, out);
}